// Round 14
// baseline (153.692 us; speedup 1.0000x reference)
//
#include <hip/hip_runtime.h>
#include <hip/hip_bf16.h>
#include <stdint.h>

#define SC_LOG2E 0.18033688011112042f  // (1/8) * log2(e)

typedef __attribute__((ext_vector_type(8))) short short8;
typedef __attribute__((ext_vector_type(4))) short short4v;
typedef __attribute__((ext_vector_type(4))) float f32x4;

__device__ __forceinline__ unsigned short f2bf(float f) {
  unsigned int u = __float_as_uint(f);
  u += 0x7fffu + ((u >> 16) & 1u);
  return (unsigned short)(u >> 16);
}

// packed f32x2 -> bf16x2 (RNE), compiler-known intrinsic (v_cvt_pk_bf16_f32)
__device__ __forceinline__ unsigned int pkbf(float a, float b) {
  union { __hip_bfloat162 h; unsigned int u; } cv;
  cv.h = __float22bfloat162_rn(float2{a, b});
  return cv.u;
}

__device__ __forceinline__ void gload_lds16(const void* g, void* l) {
  __builtin_amdgcn_global_load_lds((const __attribute__((address_space(1))) void*)g,
                                   (__attribute__((address_space(3))) void*)l,
                                   16, 0, 0);
}

__device__ __forceinline__ f32x4 mfma16(short8 a, short8 b, f32x4 c) {
  return __builtin_amdgcn_mfma_f32_16x16x32_bf16(a, b, c, 0, 0, 0);
}

// ds_read_b64_tr_b16 slot model (m156, HW-verified r7): each lane addresses its
// OWN 8-byte slot (base + l15*4 elems); HW permutes within the 16-lane group so
// lane g receives column g of the group's 128B [4 rows][16 cols] bf16 block:
// elem j = window[j*16 + g].
__device__ __forceinline__ short4v tr_read(const unsigned short* p) {
  short4v r;
  asm volatile("ds_read_b64_tr_b16 %0, %1"
               : "=v"(r)
               : "v"((const __attribute__((address_space(3))) unsigned short*)p));
  return r;
}

__device__ __forceinline__ short8 cat44(short4v lo, short4v hi) {
  return __builtin_shufflevector(lo, hi, 0, 1, 2, 3, 4, 5, 6, 7);
}

// ---------------- fused prep: cast x (512 blocks) | W transpose (1024 blocks) ----
__global__ __launch_bounds__(256) void prep_k(
    const float* __restrict__ x, unsigned short* __restrict__ xb,
    const float* __restrict__ wq, const float* __restrict__ wk,
    const float* __restrict__ wv, const float* __restrict__ wo,
    unsigned short* __restrict__ wqkv_t, unsigned short* __restrict__ wo_t) {
  __shared__ float tile[64 * 65];
  int bid = blockIdx.x;
  if (bid < 512) {
    int gr = bid;
    int c4 = threadIdx.x;
    const float4* p = (const float4*)(x + (size_t)gr * 16384) + c4;
#pragma unroll
    for (int t = 0; t < 16; ++t) {
      float4 v = p[(size_t)t * 256];
      ushort4 o;
      o.x = f2bf(v.x); o.y = f2bf(v.y); o.z = f2bf(v.z); o.w = f2bf(v.w);
      ((ushort4*)xb)[(size_t)(gr * 16 + t) * 256 + c4] = o;
    }
  } else {
    int idx = bid - 512;
    int z = idx >> 8, rem = idx & 255;
    const float* src = (z == 0) ? wq : (z == 1) ? wk : (z == 2) ? wv : wo;
    unsigned short* dst = (z == 3) ? wo_t : (wqkv_t + (size_t)z * 1048576);
    float scale = (z == 0) ? SC_LOG2E : 1.0f;
    int tc = (rem & 15) * 64, tr = (rem >> 4) * 64;
    int cx = threadIdx.x & 63, ry = threadIdx.x >> 6;
#pragma unroll
    for (int i = 0; i < 16; ++i) {
      int r = ry + i * 4;
      tile[r * 65 + cx] = src[(size_t)(tr + r) * 1024 + tc + cx];
    }
    __syncthreads();
#pragma unroll
    for (int i = 0; i < 16; ++i) {
      int r = ry + i * 4;
      dst[(size_t)(tc + r) * 1024 + tr + cx] = f2bf(tile[cx * 65 + r] * scale);
    }
  }
}

// ------- 256x256 fine-phase GEMM (T1+T2+T3+T4+T5) + fused side-sum epilogue ------
// 512 thr = 8 waves (2M x 4N); BK=64; 128KB LDS dbuf. 4 fine phases per K-tile:
//  P1 {ds_read A-half0(8)+B-half0(4) | stage A1(t+1) | vmcnt(4) | bar | 16 MFMA | bar}
//  P2 {ds_read B-half1(4)            | stage B1(t+1) | vmcnt(4) | bar | 16 MFMA | bar}
//  P3 {ds_read A-half1(8)            | stage B2(t+1) |    -     | bar | 16 MFMA | bar}
//  P4 {                                stage A2(t+1) | vmcnt(4) | bar | 16 MFMA | bar}
// Ledger: stage of tile t+1 goes to the OTHER buffer (no alias with t's reads);
// each end-of-phase vmcnt(4) leaves exactly the 2 newest half-tiles (4 loads)
// outstanding, guaranteeing the region read after the NEXT barrier has landed.
// Last tile (no stages): vmcnt tightens to 2 (P1) / 0 (P2). Never drains mid-loop.
__global__ __launch_bounds__(512, 2) void gemm256_k(
    const unsigned short* __restrict__ A, const unsigned short* __restrict__ Bt,
    unsigned short* __restrict__ C, int N, int K, int nbn,
    unsigned short* __restrict__ sidekv) {
  __shared__ unsigned short lds[2][2][16384];  // [buf][A|B][256*64]
  int nwg = gridDim.x, cpx = nwg >> 3;
  int bid = blockIdx.x;
  bid = (bid & 7) * cpx + (bid >> 3);  // XCD swizzle (grid % 8 == 0)
  int bm = bid / nbn, bn = bid % nbn;
  int lane = threadIdx.x & 63, w = threadIdx.x >> 6;
  int wm = w >> 2, wn = w & 3;
  int l15 = lane & 15, lg = lane >> 4;
  int lrow = lane >> 3;
  int lcol = ((lane & 7) ^ lrow) * 8;  // pre-swizzled source col granule
  const int KT = K >> 6;

  const unsigned short* Ab = A + ((size_t)bm * 256 + lrow) * K + lcol;
  const unsigned short* Bb = Bt + ((size_t)bn * 256 + lrow) * K + lcol;

  f32x4 zero4 = {0.f, 0.f, 0.f, 0.f};
  f32x4 acc[8][4];
#pragma unroll
  for (int i = 0; i < 8; ++i)
#pragma unroll
    for (int j = 0; j < 4; ++j) acc[i][j] = zero4;

  // stage one 16KB half-tile (2 x gload_lds per thread) of K-tile t
  // kinds: 0=A1 rows{0-63,128-191} 1=A2{64-127,192-255} 2=B1{even 32-grp} 3=B2{odd}
  auto stage = [&](int kind, int t) {
    if (t >= KT) return;
    const unsigned short* src = (kind < 2) ? Ab : Bb;
#pragma unroll
    for (int i = 0; i < 2; ++i) {
      int q = i * 64 + w * 8;
      int r0;
      if (kind == 0)      r0 = (q & 63) + ((q >> 6) << 7);
      else if (kind == 1) r0 = (q & 63) + ((q >> 6) << 7) + 64;
      else if (kind == 2) r0 = (q & 31) + ((q >> 5) << 6);
      else                r0 = (q & 31) + ((q >> 5) << 6) + 32;
      gload_lds16(src + (size_t)r0 * K + t * 64,
                  &lds[t & 1][kind < 2 ? 0 : 1][r0 * 64]);
    }
  };
  auto ldA = [&](const char* buf, int mi, int kk) -> short8 {
    int r = wm * 128 + mi * 16 + l15;
    return *(const short8*)(buf + r * 128 +
                            2 * ((kk * 32 + lg * 8) ^ ((l15 & 7) * 8)));
  };
  auto ldB = [&](const char* buf, int ni, int kk) -> short8 {
    int r = wn * 64 + ni * 16 + l15;
    return *(const short8*)(buf + r * 128 +
                            2 * ((kk * 32 + lg * 8) ^ ((l15 & 7) * 8)));
  };

  // prologue: tile0 all 4 half-tiles; vmcnt(4) -> A1(0),B1(0) landed
  stage(0, 0); stage(2, 0); stage(3, 0); stage(1, 0);
  asm volatile("s_waitcnt vmcnt(4)" ::: "memory");
  __builtin_amdgcn_s_barrier();
  __builtin_amdgcn_sched_barrier(0);

  for (int t = 0; t < KT; ++t) {
    const char* bufA = (const char*)&lds[t & 1][0][0];
    const char* bufB = (const char*)&lds[t & 1][1][0];
    bool nt = (t + 1 < KT);
    short8 aF[4][2], b0[2][2], b1[2][2];
    // ================= P1: quadrant (m0,n0) =================
#pragma unroll
    for (int mi = 0; mi < 4; ++mi)
#pragma unroll
      for (int kk = 0; kk < 2; ++kk) aF[mi][kk] = ldA(bufA, mi, kk);
#pragma unroll
    for (int ni = 0; ni < 2; ++ni)
#pragma unroll
      for (int kk = 0; kk < 2; ++kk) b0[ni][kk] = ldB(bufB, ni, kk);
    stage(0, t + 1);
    if (nt) asm volatile("s_waitcnt vmcnt(4)" ::: "memory");
    else    asm volatile("s_waitcnt vmcnt(2)" ::: "memory");
    __builtin_amdgcn_s_barrier();
    __builtin_amdgcn_sched_barrier(0);
    __builtin_amdgcn_s_setprio(1);
#pragma unroll
    for (int kk = 0; kk < 2; ++kk)
#pragma unroll
      for (int mi = 0; mi < 4; ++mi)
#pragma unroll
        for (int ni = 0; ni < 2; ++ni)
          acc[mi][ni] = mfma16(aF[mi][kk], b0[ni][kk], acc[mi][ni]);
    __builtin_amdgcn_s_setprio(0);
    __builtin_amdgcn_s_barrier();
    __builtin_amdgcn_sched_barrier(0);
    // ================= P2: quadrant (m0,n1) =================
#pragma unroll
    for (int ni = 0; ni < 2; ++ni)
#pragma unroll
      for (int kk = 0; kk < 2; ++kk) b1[ni][kk] = ldB(bufB, ni + 2, kk);
    stage(2, t + 1);
    if (nt) asm volatile("s_waitcnt vmcnt(4)" ::: "memory");
    else    asm volatile("s_waitcnt vmcnt(0)" ::: "memory");
    __builtin_amdgcn_s_barrier();
    __builtin_amdgcn_sched_barrier(0);
    __builtin_amdgcn_s_setprio(1);
#pragma unroll
    for (int kk = 0; kk < 2; ++kk)
#pragma unroll
      for (int mi = 0; mi < 4; ++mi)
#pragma unroll
        for (int ni = 0; ni < 2; ++ni)
          acc[mi][ni + 2] = mfma16(aF[mi][kk], b1[ni][kk], acc[mi][ni + 2]);
    __builtin_amdgcn_s_setprio(0);
    __builtin_amdgcn_s_barrier();
    __builtin_amdgcn_sched_barrier(0);
    // ================= P3: quadrant (m1,n1) =================
#pragma unroll
    for (int mi = 0; mi < 4; ++mi)
#pragma unroll
      for (int kk = 0; kk < 2; ++kk) aF[mi][kk] = ldA(bufA, mi + 4, kk);
    stage(3, t + 1);
    __builtin_amdgcn_s_barrier();
    __builtin_amdgcn_sched_barrier(0);
    __builtin_amdgcn_s_setprio(1);
#pragma unroll
    for (int kk = 0; kk < 2; ++kk)
#pragma unroll
      for (int mi = 0; mi < 4; ++mi)
#pragma unroll
        for (int ni = 0; ni < 2; ++ni)
          acc[mi + 4][ni + 2] = mfma16(aF[mi][kk], b1[ni][kk], acc[mi + 4][ni + 2]);
    __builtin_amdgcn_s_setprio(0);
    __builtin_amdgcn_s_barrier();
    __builtin_amdgcn_sched_barrier(0);
    // ================= P4: quadrant (m1,n0) =================
    stage(1, t + 1);
    if (nt) asm volatile("s_waitcnt vmcnt(4)" ::: "memory");
    __builtin_amdgcn_s_barrier();
    __builtin_amdgcn_sched_barrier(0);
    __builtin_amdgcn_s_setprio(1);
#pragma unroll
    for (int kk = 0; kk < 2; ++kk)
#pragma unroll
      for (int mi = 0; mi < 4; ++mi)
#pragma unroll
        for (int ni = 0; ni < 2; ++ni)
          acc[mi + 4][ni] = mfma16(aF[mi][kk], b0[ni][kk], acc[mi + 4][ni]);
    __builtin_amdgcn_s_setprio(0);
    __builtin_amdgcn_s_barrier();
    __builtin_amdgcn_sched_barrier(0);
  }

#pragma unroll
  for (int mi = 0; mi < 8; ++mi) {
    size_t row = (size_t)bm * 256 + wm * 128 + mi * 16 + lg * 4;
#pragma unroll
    for (int ni = 0; ni < 4; ++ni) {
      size_t col = (size_t)bn * 256 + wn * 64 + ni * 16 + l15;
#pragma unroll
      for (int r = 0; r < 4; ++r)
        C[(row + r) * N + col] = f2bf(acc[mi][ni][r]);
    }
  }
  if (sidekv && bn >= 4) {
    // 16-row g-group per (wm,mi); reduce r in-lane, lg groups via shfl
    int gg = bm * 16 + wm * 8;
    int colb = bn * 256 - 1024 + wn * 64;
#pragma unroll
    for (int mi = 0; mi < 8; ++mi) {
#pragma unroll
      for (int ni = 0; ni < 4; ++ni) {
        float s = (acc[mi][ni][0] + acc[mi][ni][1]) +
                  (acc[mi][ni][2] + acc[mi][ni][3]);
        s += __shfl_xor(s, 16);
        s += __shfl_xor(s, 32);
        if (lg == 0)
          sidekv[(size_t)(gg + mi) * 2048 + colb + ni * 16 + l15] = f2bf(s);
      }
    }
  }
}

// ---------------- GEMM m97 structure (out projection, f32 out) ----------------
__global__ __launch_bounds__(256) void gemm_bt_k(
    const unsigned short* __restrict__ A, const unsigned short* __restrict__ Bt,
    float* __restrict__ Cv, int N, int K, int nbn) {
  __shared__ unsigned short Alds[128 * 64];
  __shared__ unsigned short Blds[128 * 64];
  int bid = blockIdx.x;
  int bm = bid / nbn, bn = bid % nbn;
  int lane = threadIdx.x & 63, wid = threadIdx.x >> 6;
  int wr = wid >> 1, wc = wid & 1;
  int l15 = lane & 15, lg = lane >> 4;

  f32x4 zero4 = {0.f, 0.f, 0.f, 0.f};
  f32x4 acc[4][4];
#pragma unroll
  for (int i = 0; i < 4; ++i)
#pragma unroll
    for (int j = 0; j < 4; ++j) acc[i][j] = zero4;

  int srow[4], scol[4];
#pragma unroll
  for (int i = 0; i < 4; ++i) {
    int seg = wid * 4 + i;
    int r = seg * 8 + (lane >> 3);
    srow[i] = r;
    scol[i] = ((lane & 7) ^ (r & 7)) * 8;
  }
  size_t arow0 = (size_t)bm * 128, brow0 = (size_t)bn * 128;

  int ksteps = K >> 6;
  for (int ks = 0; ks < ksteps; ++ks) {
    int k0 = ks << 6;
#pragma unroll
    for (int i = 0; i < 4; ++i) {
      gload_lds16(A + (arow0 + srow[i]) * K + k0 + scol[i],
                  (char*)Alds + (wid * 4 + i) * 1024);
      gload_lds16(Bt + (brow0 + srow[i]) * K + k0 + scol[i],
                  (char*)Blds + (wid * 4 + i) * 1024);
    }
    __syncthreads();
#pragma unroll
    for (int kk = 0; kk < 2; ++kk) {
      short8 af[4], bfr[4];
#pragma unroll
      for (int mi = 0; mi < 4; ++mi) {
        int r = wr * 64 + mi * 16 + l15;
        af[mi] = *(const short8*)((const char*)Alds + r * 128 +
                                  ((kk * 64 + lg * 16) ^ ((r & 7) << 4)));
      }
#pragma unroll
      for (int ni = 0; ni < 4; ++ni) {
        int r = wc * 64 + ni * 16 + l15;
        bfr[ni] = *(const short8*)((const char*)Blds + r * 128 +
                                   ((kk * 64 + lg * 16) ^ ((r & 7) << 4)));
      }
#pragma unroll
      for (int mi = 0; mi < 4; ++mi)
#pragma unroll
        for (int ni = 0; ni < 4; ++ni)
          acc[mi][ni] = mfma16(af[mi], bfr[ni], acc[mi][ni]);
    }
    __syncthreads();
  }
  int rq = lg << 2;
#pragma unroll
  for (int mi = 0; mi < 4; ++mi) {
    size_t row = arow0 + wr * 64 + mi * 16 + rq;
#pragma unroll
    for (int ni = 0; ni < 4; ++ni) {
      size_t col = brow0 + wc * 64 + ni * 16 + l15;
#pragma unroll
      for (int r = 0; r < 4; ++r)
        Cv[(row + r) * N + col] = acc[mi][ni][r];
    }
  }
}

// ---------------- fused local+global flash attention (m=0 softmax) ----------------
// QBLK=256: grid = B*H*16; block = 512 (8 waves x 32 q-rows). K/V chunk staged once
// per 256 q-rows. qkv: [8192][3072]; side: [512][2048]; LDS 48KB.
__global__ __launch_bounds__(512) void attn_k(
    const unsigned short* __restrict__ qkv,
    const unsigned short* __restrict__ side,
    unsigned short* __restrict__ y) {  // [B*L][1024]
  const int L = 4096, G = 256;
  __shared__ unsigned short K0[4096], V0[4096];  // K: [key][d] swizzled; V: subtiled
  __shared__ unsigned short K1[4096], V1[4096];
  __shared__ unsigned short Pt[8][1024];         // per-wave P^T half [32k][32q]

  int bid = blockIdx.x;
  int n = bid & 15, h = (bid >> 4) & 15, b = bid >> 8;
  int lane = threadIdx.x & 63, wid = threadIdx.x >> 6;  // wid 0..7
  int l15 = lane & 15, lg = lane >> 4, rq = lg << 2;

  short8 qf[2][2];
  {
    size_t rowb = (size_t)b * L + n * 256 + wid * 32;
#pragma unroll
    for (int qt = 0; qt < 2; ++qt)
#pragma unroll
      for (int kk = 0; kk < 2; ++kk)
        qf[qt][kk] = *(const short8*)(qkv + (rowb + qt * 16 + l15) * 3072 +
                                      h * 64 + kk * 32 + lg * 8);
  }

  f32x4 zero4 = {0.f, 0.f, 0.f, 0.f};
  f32x4 accO[2][4], accSum[2];
#pragma unroll
  for (int qt = 0; qt < 2; ++qt) {
    accSum[qt] = zero4;
#pragma unroll
    for (int dt = 0; dt < 4; ++dt) accO[qt][dt] = zero4;
  }

  short8 onesf;
  {
    short o = (l15 == 0) ? (short)0x3F80 : (short)0;  // bf16 1.0 in B row 0
    onesf = (short8){o, o, o, o, o, o, o, o};
  }

  int clo = (n == 0) ? 2 : 0, chi = (n == 15) ? 6 : 8;
  int nloc = chi - clo, goff = 8 - nloc;
  int m = nloc + 4;
  unsigned short* pt = Pt[wid];

  auto stage = [&](int c, unsigned short* Kl, unsigned short* Vl) {
    bool isg = c >= 8;
    int r = wid * 8 + (lane >> 3);
    int sl = ((lane & 7) ^ (r & 7)) * 8;
    int S = r;
    int di = S >> 4, ks = (S >> 3) & 1, lgg = (S >> 1) & 3, half = S & 1;
    int k = ks * 32 + lgg * 8 + half * 4 + ((lane & 7) >> 1);
    int d = di * 16 + (lane & 1) * 8;
    const unsigned short *ksrc, *vsrc;
    if (!isg) {
      int rowbase = b * L + n * 256 - 128 + c * 64;  // in [0,L-64] after trim
      ksrc = qkv + (size_t)(rowbase + r) * 3072 + 1024 + h * 64 + sl;
      vsrc = qkv + (size_t)(rowbase + k) * 3072 + 2048 + h * 64 + d;
    } else {
      int rowbase = b * G + (c - 8) * 64;
      ksrc = side + (size_t)(rowbase + r) * 2048 + h * 64 + sl;
      vsrc = side + (size_t)(rowbase + k) * 2048 + 1024 + h * 64 + d;
    }
    gload_lds16(ksrc, (char*)Kl + wid * 1024);
    gload_lds16(vsrc, (char*)Vl + wid * 1024);
  };

  auto compute = [&](int c, const unsigned short* Kl, const unsigned short* Vl) {
    bool isg = c >= 8;
    int d0 = c * 64 - 128 - wid * 32;  // rel of (key0, wave q0)
    if (!isg) {
      if (d0 >= 159 || d0 <= -191) return;  // wave-chunk fully masked
    }
    bool partial = !isg && !(d0 >= -96 && d0 <= 64);

    f32x4 sacc[2][4];
#pragma unroll
    for (int qt = 0; qt < 2; ++qt)
#pragma unroll
      for (int kt = 0; kt < 4; ++kt) sacc[qt][kt] = zero4;
    __builtin_amdgcn_s_setprio(1);
#pragma unroll
    for (int kk = 0; kk < 2; ++kk) {
      short8 kf[4];
#pragma unroll
      for (int kt = 0; kt < 4; ++kt) {
        int r = kt * 16 + l15;
        kf[kt] = *(const short8*)((const char*)Kl + r * 128 +
                                  ((kk * 64 + lg * 16) ^ ((r & 7) << 4)));
      }
#pragma unroll
      for (int qt = 0; qt < 2; ++qt)
#pragma unroll
        for (int kt = 0; kt < 4; ++kt)
          sacc[qt][kt] = mfma16(qf[qt][kk], kf[kt], sacc[qt][kt]);
    }
    __builtin_amdgcn_s_setprio(0);
    if (partial) {
      int relc = d0 + l15 - rq;
#pragma unroll
      for (int qt = 0; qt < 2; ++qt)
#pragma unroll
        for (int kt = 0; kt < 4; ++kt)
#pragma unroll
          for (int r = 0; r < 4; ++r) {
            int rel = relc + kt * 16 - qt * 16 - r;
            sacc[qt][kt][r] =
                ((unsigned)(rel + 127) <= 254u) ? sacc[qt][kt][r] : -1e30f;
          }
    }
#pragma unroll
    for (int ks = 0; ks < 2; ++ks) {
#pragma unroll
      for (int qt = 0; qt < 2; ++qt)
#pragma unroll
        for (int k2 = 0; k2 < 2; ++k2) {
          int kt = ks * 2 + k2;
          uint2 pk;
          pk.x = pkbf(__builtin_amdgcn_exp2f(sacc[qt][kt][0]),
                      __builtin_amdgcn_exp2f(sacc[qt][kt][1]));
          pk.y = pkbf(__builtin_amdgcn_exp2f(sacc[qt][kt][2]),
                      __builtin_amdgcn_exp2f(sacc[qt][kt][3]));
          *(uint2*)(pt + (k2 * 8 + ((l15 >> 2) << 1) + qt) * 64 +
                    (l15 & 3) * 16 + rq) = pk;
        }
      asm volatile("s_waitcnt lgkmcnt(0)" ::: "memory");  // P writes visible
      short4v palo[2], pahi[2], vlo[4], vhi[4];
#pragma unroll
      for (int qt = 0; qt < 2; ++qt) {
        const unsigned short* pb = pt + (lg * 4 + qt) * 64 + l15 * 4;
        palo[qt] = tr_read(pb);
        pahi[qt] = tr_read(pb + 128);
      }
#pragma unroll
      for (int dt = 0; dt < 4; ++dt) {
        const unsigned short* base =
            Vl + (((dt * 2 + ks) * 4 + lg) * 2) * 64 + l15 * 4;
        vlo[dt] = tr_read(base);
        vhi[dt] = tr_read(base + 64);
      }
      asm volatile("s_waitcnt lgkmcnt(0)" ::: "memory");
      __builtin_amdgcn_sched_barrier(0);
      __builtin_amdgcn_s_setprio(1);
#pragma unroll
      for (int qt = 0; qt < 2; ++qt) {
        short8 pa = cat44(palo[qt], pahi[qt]);
#pragma unroll
        for (int dt = 0; dt < 4; ++dt)
          accO[qt][dt] = mfma16(pa, cat44(vlo[dt], vhi[dt]), accO[qt][dt]);
        accSum[qt] = mfma16(pa, onesf, accSum[qt]);
      }
      __builtin_amdgcn_s_setprio(0);
    }
  };

  auto chunk_of = [&](int i) { return i < nloc ? i + clo : i + goff; };

  stage(chunk_of(0), K0, V0);
  __syncthreads();
  for (int i = 0; i < m; i += 2) {
    if (i + 1 < m) stage(chunk_of(i + 1), K1, V1);
    compute(chunk_of(i), K0, V0);
    __syncthreads();
    if (i + 1 >= m) break;
    if (i + 2 < m) stage(chunk_of(i + 2), K0, V0);
    compute(chunk_of(i + 1), K1, V1);
    __syncthreads();
  }

  size_t rowb = (size_t)b * L + n * 256 + wid * 32;
#pragma unroll
  for (int qt = 0; qt < 2; ++qt) {
    float inv[4];
#pragma unroll
    for (int r = 0; r < 4; ++r) {
      float s = __shfl(accSum[qt][r], lane & 48);  // col 0 lives in l15==0 lanes
      inv[r] = 1.f / (1.f + s);
    }
#pragma unroll
    for (int dt = 0; dt < 4; ++dt) {
      int col = h * 64 + dt * 16 + l15;
#pragma unroll
      for (int r = 0; r < 4; ++r)
        y[(rowb + qt * 16 + rq + r) * 1024 + col] =
            f2bf(accO[qt][dt][r] * inv[r]);
    }
  }
}

// ---------------- launch ----------------
extern "C" void kernel_launch(void* const* d_in, const int* in_sizes, int n_in,
                              void* d_out, int out_size, void* d_ws, size_t ws_size,
                              hipStream_t stream) {
  const float* x  = (const float*)d_in[0];
  const float* wq = (const float*)d_in[1];
  const float* wk = (const float*)d_in[2];
  const float* wv = (const float*)d_in[3];
  const float* wo = (const float*)d_in[4];
  char* ws = (char*)d_ws;
  const size_t MB = 1 << 20;
  unsigned short* xb     = (unsigned short*)(ws);             // 16MB; reused as y
  unsigned short* wqkv_t = (unsigned short*)(ws + 17 * MB);   // 6MB
  unsigned short* wo_t   = (unsigned short*)(ws + 23 * MB);   // 2MB
  unsigned short* qkvb   = (unsigned short*)(ws + 25 * MB);   // 48MB [8192][3072]
  unsigned short* sidekv = (unsigned short*)(ws + 73 * MB);   // 2MB [512][2048]
  unsigned short* yb     = xb;  // xb dead after QKV GEMM

  prep_k<<<1536, 256, 0, stream>>>(x, xb, wq, wk, wv, wo, wqkv_t, wo_t);
  // QKV: [8192][1024] x [3072][1024]^T -> [8192][3072], 256^2 fine-phase + side
  gemm256_k<<<32 * 12, 512, 0, stream>>>(xb, wqkv_t, qkvb, 3072, 1024, 12, sidekv);
  attn_k<<<512, 512, 0, stream>>>(qkvb, sidekv, yb);
  // out: [8192][1024] x [1024][1024]^T -> f32 d_out (m97 structure)
  gemm_bt_k<<<64 * 8, 256, 0, stream>>>(yb, wo_t, (float*)d_out, 1024, 1024, 8);
}

// Round 15
// 150.984 us; speedup vs baseline: 1.0179x; 1.0179x over previous
//
#include <hip/hip_runtime.h>
#include <hip/hip_bf16.h>
#include <stdint.h>

#define SC_LOG2E 0.18033688011112042f  // (1/8) * log2(e)

typedef __attribute__((ext_vector_type(8))) short short8;
typedef __attribute__((ext_vector_type(4))) short short4v;
typedef __attribute__((ext_vector_type(4))) float f32x4;

__device__ __forceinline__ unsigned short f2bf(float f) {
  unsigned int u = __float_as_uint(f);
  u += 0x7fffu + ((u >> 16) & 1u);
  return (unsigned short)(u >> 16);
}

// packed f32x2 -> bf16x2 (RNE), compiler-known intrinsic (v_cvt_pk_bf16_f32)
__device__ __forceinline__ unsigned int pkbf(float a, float b) {
  union { __hip_bfloat162 h; unsigned int u; } cv;
  cv.h = __float22bfloat162_rn(float2{a, b});
  return cv.u;
}

__device__ __forceinline__ void gload_lds16(const void* g, void* l) {
  __builtin_amdgcn_global_load_lds((const __attribute__((address_space(1))) void*)g,
                                   (__attribute__((address_space(3))) void*)l,
                                   16, 0, 0);
}

__device__ __forceinline__ f32x4 mfma16(short8 a, short8 b, f32x4 c) {
  return __builtin_amdgcn_mfma_f32_16x16x32_bf16(a, b, c, 0, 0, 0);
}

// ds_read_b64_tr_b16 slot model (m156, HW-verified r7): each lane addresses its
// OWN 8-byte slot (base + l15*4 elems); HW permutes within the 16-lane group so
// lane g receives column g of the group's 128B [4 rows][16 cols] bf16 block:
// elem j = window[j*16 + g].
__device__ __forceinline__ short4v tr_read(const unsigned short* p) {
  short4v r;
  asm volatile("ds_read_b64_tr_b16 %0, %1"
               : "=v"(r)
               : "v"((const __attribute__((address_space(3))) unsigned short*)p));
  return r;
}

__device__ __forceinline__ short8 cat44(short4v lo, short4v hi) {
  return __builtin_shufflevector(lo, hi, 0, 1, 2, 3, 4, 5, 6, 7);
}

// ---------------- fused prep: cast x (512 blocks) | W transpose (1024 blocks) ----
__global__ __launch_bounds__(256) void prep_k(
    const float* __restrict__ x, unsigned short* __restrict__ xb,
    const float* __restrict__ wq, const float* __restrict__ wk,
    const float* __restrict__ wv, const float* __restrict__ wo,
    unsigned short* __restrict__ wqkv_t, unsigned short* __restrict__ wo_t) {
  __shared__ float tile[64 * 65];
  int bid = blockIdx.x;
  if (bid < 512) {
    // cast x -> bf16 (16 rows of 1024 per block)
    int gr = bid;
    int c4 = threadIdx.x;  // col group of 4
    const float4* p = (const float4*)(x + (size_t)gr * 16384) + c4;
#pragma unroll
    for (int t = 0; t < 16; ++t) {
      float4 v = p[(size_t)t * 256];
      ushort4 o;
      o.x = f2bf(v.x); o.y = f2bf(v.y); o.z = f2bf(v.z); o.w = f2bf(v.w);
      ((ushort4*)xb)[(size_t)(gr * 16 + t) * 256 + c4] = o;
    }
  } else {
    // transpose 4x [1024][1024] f32 weights -> bf16 [N][K]; Wq scaled by SC_LOG2E
    int idx = bid - 512;
    int z = idx >> 8, rem = idx & 255;
    const float* src = (z == 0) ? wq : (z == 1) ? wk : (z == 2) ? wv : wo;
    unsigned short* dst = (z == 3) ? wo_t : (wqkv_t + (size_t)z * 1048576);
    float scale = (z == 0) ? SC_LOG2E : 1.0f;
    int tc = (rem & 15) * 64, tr = (rem >> 4) * 64;
    int cx = threadIdx.x & 63, ry = threadIdx.x >> 6;
#pragma unroll
    for (int i = 0; i < 16; ++i) {
      int r = ry + i * 4;
      tile[r * 65 + cx] = src[(size_t)(tr + r) * 1024 + tc + cx];
    }
    __syncthreads();
#pragma unroll
    for (int i = 0; i < 16; ++i) {
      int r = ry + i * 4;
      dst[(size_t)(tc + r) * 1024 + tr + cx] = f2bf(tile[cx * 65 + r] * scale);
    }
  }
}

// ---------------- GEMM m97 structure: C[M][N] = A[M][K] * Bt[N][K]^T ----------------
// SIDE: fused side-K/V epilogue — for k/v blocks (bn>=8), also emit 16-row block
// sums of the f32 accumulators into sidekv [512][2048] (linearity: sum of k rows
// = projection of summed x rows). Epilogue-only addition; hot loop untouched.
template <bool F32OUT, bool SIDE>
__global__ __launch_bounds__(256) void gemm_bt_k(
    const unsigned short* __restrict__ A, const unsigned short* __restrict__ Bt,
    void* __restrict__ Cv, int M, int N, int K, int nbn,
    unsigned short* __restrict__ sidekv) {
  __shared__ unsigned short Alds[128 * 64];
  __shared__ unsigned short Blds[128 * 64];
  int bid = blockIdx.x;
  int bm = bid / nbn, bn = bid % nbn;
  int lane = threadIdx.x & 63, wid = threadIdx.x >> 6;
  int wr = wid >> 1, wc = wid & 1;
  int l15 = lane & 15, lg = lane >> 4;

  f32x4 zero4 = {0.f, 0.f, 0.f, 0.f};
  f32x4 acc[4][4];
#pragma unroll
  for (int i = 0; i < 4; ++i)
#pragma unroll
    for (int j = 0; j < 4; ++j) acc[i][j] = zero4;

  int srow[4], scol[4];
#pragma unroll
  for (int i = 0; i < 4; ++i) {
    int seg = wid * 4 + i;
    int r = seg * 8 + (lane >> 3);
    srow[i] = r;
    scol[i] = ((lane & 7) ^ (r & 7)) * 8;
  }
  size_t arow0 = (size_t)bm * 128, brow0 = (size_t)bn * 128;

  int ksteps = K >> 6;
  for (int ks = 0; ks < ksteps; ++ks) {
    int k0 = ks << 6;
#pragma unroll
    for (int i = 0; i < 4; ++i) {
      gload_lds16(A + (arow0 + srow[i]) * K + k0 + scol[i],
                  (char*)Alds + (wid * 4 + i) * 1024);
      gload_lds16(Bt + (brow0 + srow[i]) * K + k0 + scol[i],
                  (char*)Blds + (wid * 4 + i) * 1024);
    }
    __syncthreads();
#pragma unroll
    for (int kk = 0; kk < 2; ++kk) {
      short8 af[4], bfr[4];
#pragma unroll
      for (int mi = 0; mi < 4; ++mi) {
        int r = wr * 64 + mi * 16 + l15;
        af[mi] = *(const short8*)((const char*)Alds + r * 128 +
                                  ((kk * 64 + lg * 16) ^ ((r & 7) << 4)));
      }
#pragma unroll
      for (int ni = 0; ni < 4; ++ni) {
        int r = wc * 64 + ni * 16 + l15;
        bfr[ni] = *(const short8*)((const char*)Blds + r * 128 +
                                   ((kk * 64 + lg * 16) ^ ((r & 7) << 4)));
      }
#pragma unroll
      for (int mi = 0; mi < 4; ++mi)
#pragma unroll
        for (int ni = 0; ni < 4; ++ni)
          acc[mi][ni] = mfma16(af[mi], bfr[ni], acc[mi][ni]);
    }
    __syncthreads();
  }
  int rq = lg << 2;
#pragma unroll
  for (int mi = 0; mi < 4; ++mi) {
    size_t row = arow0 + wr * 64 + mi * 16 + rq;
#pragma unroll
    for (int ni = 0; ni < 4; ++ni) {
      size_t col = brow0 + wc * 64 + ni * 16 + l15;
#pragma unroll
      for (int r = 0; r < 4; ++r) {
        if (F32OUT)
          ((float*)Cv)[(row + r) * N + col] = acc[mi][ni][r];
        else
          ((unsigned short*)Cv)[(row + r) * N + col] = f2bf(acc[mi][ni][r]);
      }
    }
  }
  if (SIDE && bn >= 8) {
    // each (wr,mi) 16-row group = one g-group; reduce r in-lane, lg via shfl
    int gg = bm * 8 + wr * 4;
    int colb = bn * 128 - 1024 + wc * 64;
#pragma unroll
    for (int mi = 0; mi < 4; ++mi) {
#pragma unroll
      for (int ni = 0; ni < 4; ++ni) {
        float s = (acc[mi][ni][0] + acc[mi][ni][1]) +
                  (acc[mi][ni][2] + acc[mi][ni][3]);
        s += __shfl_xor(s, 16);
        s += __shfl_xor(s, 32);
        if (lg == 0)
          sidekv[(size_t)(gg + mi) * 2048 + colb + ni * 16 + l15] = f2bf(s);
      }
    }
  }
}

// ---------------- fused local+global flash attention (m=0 softmax) ----------------
// QBLK=256: grid = B*H*16 (n fastest); block = 512 (8 waves x 32 q-rows).
// Each K/V chunk staged ONCE per 256 q-rows -> stage bytes -40%, barriers -40%.
// qkv: [8192][3072] token q|k|v; side: [512][2048] sk|sv; LDS 48KB.
__global__ __launch_bounds__(512) void attn_k(
    const unsigned short* __restrict__ qkv,
    const unsigned short* __restrict__ side,
    unsigned short* __restrict__ y) {  // [B*L][1024]
  const int L = 4096, G = 256;
  __shared__ unsigned short K0[4096], V0[4096];  // K: [key][d] swizzled; V: subtiled
  __shared__ unsigned short K1[4096], V1[4096];
  __shared__ unsigned short Pt[8][1024];         // per-wave P^T half [32k][32q]

  int bid = blockIdx.x;
  int n = bid & 15, h = (bid >> 4) & 15, b = bid >> 8;
  int lane = threadIdx.x & 63, wid = threadIdx.x >> 6;  // wid 0..7
  int l15 = lane & 15, lg = lane >> 4, rq = lg << 2;

  short8 qf[2][2];
  {
    size_t rowb = (size_t)b * L + n * 256 + wid * 32;
#pragma unroll
    for (int qt = 0; qt < 2; ++qt)
#pragma unroll
      for (int kk = 0; kk < 2; ++kk)
        qf[qt][kk] = *(const short8*)(qkv + (rowb + qt * 16 + l15) * 3072 +
                                      h * 64 + kk * 32 + lg * 8);
  }

  f32x4 zero4 = {0.f, 0.f, 0.f, 0.f};
  f32x4 accO[2][4], accSum[2];
#pragma unroll
  for (int qt = 0; qt < 2; ++qt) {
    accSum[qt] = zero4;
#pragma unroll
    for (int dt = 0; dt < 4; ++dt) accO[qt][dt] = zero4;
  }

  short8 onesf;
  {
    short o = (l15 == 0) ? (short)0x3F80 : (short)0;  // bf16 1.0 in B row 0
    onesf = (short8){o, o, o, o, o, o, o, o};
  }

  // local 64-key chunks c in [clo,chi): rowbase = b*L + n*256 - 128 + c*64
  int clo = (n == 0) ? 2 : 0, chi = (n == 15) ? 6 : 8;
  int nloc = chi - clo, goff = 8 - nloc;
  int m = nloc + 4;
  unsigned short* pt = Pt[wid];

  auto stage = [&](int c, unsigned short* Kl, unsigned short* Vl) {
    bool isg = c >= 8;
    // 8 waves, 8 segs each for K and V: wave wid stages seg wid (1KB each)
    int r = wid * 8 + (lane >> 3);
    int sl = ((lane & 7) ^ (r & 7)) * 8;
    int S = r;
    int di = S >> 4, ks = (S >> 3) & 1, lgg = (S >> 1) & 3, half = S & 1;
    int k = ks * 32 + lgg * 8 + half * 4 + ((lane & 7) >> 1);
    int d = di * 16 + (lane & 1) * 8;
    const unsigned short *ksrc, *vsrc;
    if (!isg) {
      int rowbase = b * L + n * 256 - 128 + c * 64;  // in [0,L-64] after trim
      ksrc = qkv + (size_t)(rowbase + r) * 3072 + 1024 + h * 64 + sl;
      vsrc = qkv + (size_t)(rowbase + k) * 3072 + 2048 + h * 64 + d;
    } else {
      int rowbase = b * G + (c - 8) * 64;
      ksrc = side + (size_t)(rowbase + r) * 2048 + h * 64 + sl;
      vsrc = side + (size_t)(rowbase + k) * 2048 + 1024 + h * 64 + d;
    }
    gload_lds16(ksrc, (char*)Kl + wid * 1024);
    gload_lds16(vsrc, (char*)Vl + wid * 1024);
  };

  auto compute = [&](int c, const unsigned short* Kl, const unsigned short* Vl) {
    bool isg = c >= 8;
    int d0 = c * 64 - 128 - wid * 32;  // rel of (key0, wave q0)
    if (!isg) {
      if (d0 >= 159 || d0 <= -191) return;  // wave-chunk fully masked
    }
    bool partial = !isg && !(d0 >= -96 && d0 <= 64);

    f32x4 sacc[2][4];
#pragma unroll
    for (int qt = 0; qt < 2; ++qt)
#pragma unroll
      for (int kt = 0; kt < 4; ++kt) sacc[qt][kt] = zero4;
    __builtin_amdgcn_s_setprio(1);
#pragma unroll
    for (int kk = 0; kk < 2; ++kk) {
      short8 kf[4];
#pragma unroll
      for (int kt = 0; kt < 4; ++kt) {
        int r = kt * 16 + l15;
        kf[kt] = *(const short8*)((const char*)Kl + r * 128 +
                                  ((kk * 64 + lg * 16) ^ ((r & 7) << 4)));
      }
#pragma unroll
      for (int qt = 0; qt < 2; ++qt)
#pragma unroll
        for (int kt = 0; kt < 4; ++kt)
          sacc[qt][kt] = mfma16(qf[qt][kk], kf[kt], sacc[qt][kt]);
    }
    __builtin_amdgcn_s_setprio(0);
    if (partial) {
      int relc = d0 + l15 - rq;
#pragma unroll
      for (int qt = 0; qt < 2; ++qt)
#pragma unroll
        for (int kt = 0; kt < 4; ++kt)
#pragma unroll
          for (int r = 0; r < 4; ++r) {
            int rel = relc + kt * 16 - qt * 16 - r;
            sacc[qt][kt][r] =
                ((unsigned)(rel + 127) <= 254u) ? sacc[qt][kt][r] : -1e30f;
          }
    }
    // ---- per ks-half: P^T pack (cvt_pk) + b64 write, tr_read A-frags, PV ----
#pragma unroll
    for (int ks = 0; ks < 2; ++ks) {
#pragma unroll
      for (int qt = 0; qt < 2; ++qt)
#pragma unroll
        for (int k2 = 0; k2 < 2; ++k2) {
          int kt = ks * 2 + k2;
          uint2 pk;
          pk.x = pkbf(__builtin_amdgcn_exp2f(sacc[qt][kt][0]),
                      __builtin_amdgcn_exp2f(sacc[qt][kt][1]));
          pk.y = pkbf(__builtin_amdgcn_exp2f(sacc[qt][kt][2]),
                      __builtin_amdgcn_exp2f(sacc[qt][kt][3]));
          // subtile s = k2*8 + (l15>>2)*2 + qt; elem = s*64 + (l15&3)*16 + rq
          *(uint2*)(pt + (k2 * 8 + ((l15 >> 2) << 1) + qt) * 64 +
                    (l15 & 3) * 16 + rq) = pk;
        }
      asm volatile("s_waitcnt lgkmcnt(0)" ::: "memory");  // P writes visible
      short4v palo[2], pahi[2], vlo[4], vhi[4];
#pragma unroll
      for (int qt = 0; qt < 2; ++qt) {
        const unsigned short* pb = pt + (lg * 4 + qt) * 64 + l15 * 4;
        palo[qt] = tr_read(pb);         // keys lg*8+0..3 (q col l15)
        pahi[qt] = tr_read(pb + 128);   // keys lg*8+4..7
      }
#pragma unroll
      for (int dt = 0; dt < 4; ++dt) {
        const unsigned short* base =
            Vl + (((dt * 2 + ks) * 4 + lg) * 2) * 64 + l15 * 4;
        vlo[dt] = tr_read(base);        // keys lg*8+0..3 (d col l15)
        vhi[dt] = tr_read(base + 64);   // keys lg*8+4..7
      }
      asm volatile("s_waitcnt lgkmcnt(0)" ::: "memory");
      __builtin_amdgcn_sched_barrier(0);
      __builtin_amdgcn_s_setprio(1);
#pragma unroll
      for (int qt = 0; qt < 2; ++qt) {
        short8 pa = cat44(palo[qt], pahi[qt]);
#pragma unroll
        for (int dt = 0; dt < 4; ++dt)
          accO[qt][dt] = mfma16(pa, cat44(vlo[dt], vhi[dt]), accO[qt][dt]);
        accSum[qt] = mfma16(pa, onesf, accSum[qt]);
      }
      __builtin_amdgcn_s_setprio(0);
    }
  };

  auto chunk_of = [&](int i) { return i < nloc ? i + clo : i + goff; };

  stage(chunk_of(0), K0, V0);
  __syncthreads();
  for (int i = 0; i < m; i += 2) {
    if (i + 1 < m) stage(chunk_of(i + 1), K1, V1);
    compute(chunk_of(i), K0, V0);
    __syncthreads();
    if (i + 1 >= m) break;
    if (i + 2 < m) stage(chunk_of(i + 2), K0, V0);
    compute(chunk_of(i + 1), K1, V1);
    __syncthreads();
  }

  size_t rowb = (size_t)b * L + n * 256 + wid * 32;
#pragma unroll
  for (int qt = 0; qt < 2; ++qt) {
    float inv[4];
#pragma unroll
    for (int r = 0; r < 4; ++r) {
      float s = __shfl(accSum[qt][r], lane & 48);  // col 0 lives in l15==0 lanes
      inv[r] = 1.f / (1.f + s);
    }
#pragma unroll
    for (int dt = 0; dt < 4; ++dt) {
      int col = h * 64 + dt * 16 + l15;
#pragma unroll
      for (int r = 0; r < 4; ++r)
        y[(rowb + qt * 16 + rq + r) * 1024 + col] =
            f2bf(accO[qt][dt][r] * inv[r]);
    }
  }
}

// ---------------- launch ----------------
extern "C" void kernel_launch(void* const* d_in, const int* in_sizes, int n_in,
                              void* d_out, int out_size, void* d_ws, size_t ws_size,
                              hipStream_t stream) {
  const float* x  = (const float*)d_in[0];
  const float* wq = (const float*)d_in[1];
  const float* wk = (const float*)d_in[2];
  const float* wv = (const float*)d_in[3];
  const float* wo = (const float*)d_in[4];
  char* ws = (char*)d_ws;
  const size_t MB = 1 << 20;
  unsigned short* xb     = (unsigned short*)(ws);             // 16MB; reused as y
  unsigned short* wqkv_t = (unsigned short*)(ws + 17 * MB);   // 6MB
  unsigned short* wo_t   = (unsigned short*)(ws + 23 * MB);   // 2MB
  unsigned short* qkvb   = (unsigned short*)(ws + 25 * MB);   // 48MB [8192][3072]
  unsigned short* sidekv = (unsigned short*)(ws + 73 * MB);   // 2MB [512][2048]
  unsigned short* yb     = xb;  // xb dead after QKV GEMM

  prep_k<<<1536, 256, 0, stream>>>(x, xb, wq, wk, wv, wo, wqkv_t, wo_t);
  // QKV: [8192][1024] x [3072][1024]^T -> [8192][3072] + fused side-K/V epilogue
  gemm_bt_k<false, true><<<64 * 24, 256, 0, stream>>>(
      xb, wqkv_t, qkvb, 8192, 3072, 1024, 24, sidekv);
  attn_k<<<512, 512, 0, stream>>>(qkvb, sidekv, yb);
  // out: [8192][1024] x [1024][1024]^T -> f32 d_out
  gemm_bt_k<true, false><<<64 * 8, 256, 0, stream>>>(
      yb, wo_t, d_out, 8192, 1024, 1024, 8, nullptr);
}